// Round 8
// baseline (189.445 us; speedup 1.0000x reference)
//
#include <hip/hip_runtime.h>

#define BATCH 512
#define SEQ   512
#define VOCAB 1000
#define EMB   100
#define UNITS 64

// 2*log2(e): exp(2y) = exp2(KSCALE*y); folded into P and Whh at load time.
#define KSCALE 2.885390081777926814f

#define P_BYTES (VOCAB * UNITS * 4)  // 256000, 128B-aligned

typedef float v2f __attribute__((ext_vector_type(2)));
typedef float v4f __attribute__((ext_vector_type(4)));
typedef int   v2i __attribute__((ext_vector_type(2)));

// ---------------------------------------------------------------------------
// ONE fused persistent kernel (512 blocks x 1 wave).
//
// r7 post-mortem: the scan step is pinned at 490-560 cyc across 7 structures
// (split-2/4, no-split, register butterfly, DPP gather, 4-wave cooperative);
// r6's split-2 (492 cyc) is the floor. The remaining lever is the ~55 us
// NON-scan time: two serialized dispatches + proj wall. Evidence it's not
// proj compute: rewriting proj 4x faster (r0->r1) moved the gap by ~2 us.
//
// Phase 1: block b computes P rows {2b, 2b+1} (500 working blocks):
//   P[v][u] = KSCALE * (sum_d emb[v][d]*Wxh[d][u] + b[u] + colsum_u),
//   colsum_u = sum_i Whh[i][u]  (from the r-substitution h = 1-2r).
// Then: release-arrive on a global counter (agent scope), scan setup (wv,
// tokv -- independent of P, overlaps other blocks' phase 1), spin-acquire
// until all 512 arrived, then the r6 scan verbatim.
//
// Co-residency (G16): 512 blocks x 64 thr x ~140 VGPR -> >=4 blocks/CU
// capacity, 2/CU needed; all blocks resident, spin barrier cannot deadlock.
// Cross-XCD visibility: release/acquire at __HIP_MEMORY_SCOPE_AGENT +
// __threadfence() (device-scope) per the guide's correctness boundaries.
// Counter is zeroed each launch by hipMemsetAsync on the stream.
// ---------------------------------------------------------------------------
__global__ __launch_bounds__(64)
__attribute__((amdgpu_waves_per_eu(1, 1)))
void fused_kernel(
    const int* __restrict__ tok, const float* __restrict__ emb,
    const float* __restrict__ Wxh, const float* __restrict__ Whh,
    const float* __restrict__ bias, const float* __restrict__ Wout,
    const float* __restrict__ bout, float* __restrict__ P,
    int* __restrict__ counter, float* __restrict__ out) {
  const int row  = blockIdx.x;
  const int lane = threadIdx.x;
  const int g    = lane >> 5;   // which half of the i-dimension this lane sums
  const int m    = lane & 31;

  // ---- Phase 1: compute P rows 2*row and 2*row+1. ----
  {
    const int u = lane;
    float cs = 0.f;
#pragma unroll 8
    for (int i = 0; i < UNITS; ++i) cs += Whh[i * UNITS + u];
#pragma unroll
    for (int k = 0; k < 2; ++k) {
      const int v = 2 * row + k;
      if (v < VOCAB) {
        const float* e = emb + v * EMB;
        float a0 = 0.f, a1 = 0.f, a2 = 0.f, a3 = 0.f;
#pragma unroll
        for (int d = 0; d < EMB; d += 4) {
          a0 = fmaf(e[d + 0], Wxh[(d + 0) * UNITS + u], a0);
          a1 = fmaf(e[d + 1], Wxh[(d + 1) * UNITS + u], a1);
          a2 = fmaf(e[d + 2], Wxh[(d + 2) * UNITS + u], a2);
          a3 = fmaf(e[d + 3], Wxh[(d + 3) * UNITS + u], a3);
        }
        P[v * UNITS + u] = (((a0 + a1) + (a2 + a3)) + bias[u] + cs) * KSCALE;
      }
    }
  }
  // Release-arrive: my P rows are globally visible before the count bump.
  __threadfence();
  if (lane == 0)
    __hip_atomic_fetch_add(counter, 1, __ATOMIC_RELEASE,
                           __HIP_MEMORY_SCOPE_AGENT);

  // ---- Scan setup (independent of P; overlaps other blocks' phase 1). ----
  __shared__ __align__(16) v4f hs4[UNITS / 4];  // 64 floats (r-state)
  float* hsf = (float*)hs4;

  // Weights scaled by -2*KSCALE (r-substitution + exp2 fold):
  v2f wv0[UNITS / 4], wv1[UNITS / 4];
#pragma unroll
  for (int k2 = 0; k2 < UNITS / 4; ++k2) {
    const int i0 = 32 * g + 2 * k2;
    float ax = Whh[(i0 + 0) * UNITS + m] * (-2.f * KSCALE);
    float ay = Whh[(i0 + 1) * UNITS + m] * (-2.f * KSCALE);
    float bx = Whh[(i0 + 0) * UNITS + m + 32] * (-2.f * KSCALE);
    float by = Whh[(i0 + 1) * UNITS + m + 32] * (-2.f * KSCALE);
    asm volatile("" : "+v"(ax), "+v"(ay), "+v"(bx), "+v"(by));
    wv0[k2].x = ax; wv0[k2].y = ay;
    wv1[k2].x = bx; wv1[k2].y = by;
  }

  // All 512 tokens of this row, pre-scaled by UNITS (coalesced loads).
  int tokv[SEQ / 64];
  const int* trow = tok + (long)row * SEQ;
#pragma unroll
  for (int c = 0; c < SEQ / 64; ++c) {
    int t = trow[c * 64 + lane] * UNITS;
    asm volatile("" : "+v"(t));
    tokv[c] = t;
  }

  // h_0 = 0  <=>  r_0 = 0.5 (single wave: in-order DS pipe, no barriers).
  hsf[lane] = 0.5f;
  float r_last = 0.5f;

  // ---- Spin-acquire until all 512 blocks published their P rows. ----
  if (lane == 0) {
    while (__hip_atomic_load(counter, __ATOMIC_ACQUIRE,
                             __HIP_MEMORY_SCOPE_AGENT) < (int)gridDim.x) {
      __builtin_amdgcn_s_sleep(8);
    }
  }
  __threadfence();  // acquire side, wave-wide

  // Prefetch P row for t=0 (P valid only after the barrier).
  int tk0 = __builtin_amdgcn_readlane(tokv[0], 0);
  float a = P[(long)tk0 + lane];

  // ---- r6 scan loop, verbatim (measured floor: 492 cyc/step). ----
#pragma unroll
  for (int c = 0; c < SEQ / 64; ++c) {
#pragma unroll 2
    for (int tt = 0; tt < 64; ++tt) {
      float a_cur = a;
      // Prefetch next timestep's P row (consumed one full step later).
      int ntt = (tt + 1) & 63;
      int tkn = __builtin_amdgcn_readlane(tokv[c], ntt);
      a = P[(long)tkn + lane];

      // ---- Read only MY half of r: 8x ds_read_b128, back-to-back. ----
      v4f hq[UNITS / 8];
#pragma unroll
      for (int q = 0; q < UNITS / 8; ++q) hq[q] = hs4[(UNITS / 8) * g + q];

      // ---- Two half-dot partials, 4 independent 8-deep pk_fma chains. ----
      v2f p0a = {0.f, 0.f}, p0b = {0.f, 0.f};
      v2f p1a = {0.f, 0.f}, p1b = {0.f, 0.f};
#pragma unroll
      for (int q = 0; q < UNITS / 8; ++q) {
        v2f lo = __builtin_shufflevector(hq[q], hq[q], 0, 1);
        v2f hi = __builtin_shufflevector(hq[q], hq[q], 2, 3);
        p0a += lo * wv0[2 * q + 0];
        p0b += hi * wv0[2 * q + 1];
        p1a += lo * wv1[2 * q + 0];
        p1b += hi * wv1[2 * q + 1];
      }
      float s0 = (p0a.x + p0a.y) + (p0b.x + p0b.y);  // partial of Ky[m]
      float s1 = (p1a.x + p1a.y) + (p1b.x + p1b.y);  // partial of Ky[m+32]

      // ---- Merge halves (r1/r6-verified): y[lane] = K*y. ----
      v2i sw = __builtin_amdgcn_permlane32_swap(
          __float_as_int(s0), __float_as_int(s1), false, false);
      float y = __int_as_float(sw[0]) + __int_as_float(sw[1]) + a_cur;

      // r = rcp(exp2(Ky)+1); h = 1-2r folded into weights/P.
      float ex = __builtin_amdgcn_exp2f(y);
      float r = __builtin_amdgcn_rcpf(ex + 1.f);
      r_last = r;

      // Publish r for the next step (in-order DS pipe, no barrier needed).
      hsf[lane] = r;
    }
    if (c + 1 < SEQ / 64) {
      int tkb = __builtin_amdgcn_readlane(tokv[c + 1], 0);
      a = P[(long)tkb + lane];
    }
  }

  // h_T[lane] = 1 - 2*r_last;  out[row] = sigmoid(h_T . Wout + bout)
  float hT = fmaf(-2.f, r_last, 1.f);
  float psum = hT * Wout[lane];
#pragma unroll
  for (int off = 32; off > 0; off >>= 1) psum += __shfl_xor(psum, off);
  if (lane == 0) out[row] = 1.f / (1.f + __expf(-(psum + bout[0])));
}

extern "C" void kernel_launch(void* const* d_in, const int* in_sizes, int n_in,
                              void* d_out, int out_size, void* d_ws, size_t ws_size,
                              hipStream_t stream) {
  const int*   tok  = (const int*)  d_in[0];  // [BATCH, SEQ] int32
  const float* emb  = (const float*)d_in[1];  // [VOCAB, EMB]
  const float* Wxh  = (const float*)d_in[2];  // [EMB, UNITS]
  const float* Whh  = (const float*)d_in[3];  // [UNITS, UNITS]
  const float* bias = (const float*)d_in[4];  // [UNITS]
  const float* Wout = (const float*)d_in[5];  // [UNITS, 1]
  const float* bout = (const float*)d_in[6];  // [1]
  float* out = (float*)d_out;                 // [BATCH, 1] fp32

  float* P = (float*)d_ws;                           // VOCAB*UNITS fp32
  int* counter = (int*)((char*)d_ws + P_BYTES);      // 128B-aligned, own line

  hipMemsetAsync(counter, 0, sizeof(int), stream);   // stream-ordered, capturable
  fused_kernel<<<BATCH, 64, 0, stream>>>(tok, emb, Wxh, Whh, bias, Wout, bout,
                                         P, counter, out);
}

// Round 9
// 161.353 us; speedup vs baseline: 1.1741x; 1.1741x over previous
//
#include <hip/hip_runtime.h>

#define BATCH 512
#define SEQ   512
#define VOCAB 1000
#define EMB   100
#define UNITS 64

// 2*log2(e): exp(2y) = exp2(KSCALE*y); folded into P and Whh at load time.
#define KSCALE 2.885390081777926814f

typedef float v2f __attribute__((ext_vector_type(2)));
typedef float v4f __attribute__((ext_vector_type(4)));
typedef int   v2i __attribute__((ext_vector_type(2)));

// ---------------------------------------------------------------------------
// Kernel 1: P[v][u] = KSCALE * ( sum_d emb[v][d]*Wxh[d][u] + b[u] + colsum_u )
// colsum_u = sum_i Whh[i][u] comes from the scan's r-substitution
// (h = 1 - 2r  =>  sum_i h_i W_iu = colsum_u - 2 sum_i r_i W_iu).
// ---------------------------------------------------------------------------
__global__ __launch_bounds__(256) void proj_kernel(
    const float* __restrict__ emb, const float* __restrict__ Wxh,
    const float* __restrict__ bias, const float* __restrict__ Whh,
    float* __restrict__ P) {
  const int v = blockIdx.x * 4 + (threadIdx.x >> 6);
  const int u = threadIdx.x & 63;
  const float* e = emb + v * EMB;
  float a0 = 0.f, a1 = 0.f, a2 = 0.f, a3 = 0.f;
#pragma unroll
  for (int d = 0; d < EMB; d += 4) {
    a0 = fmaf(e[d + 0], Wxh[(d + 0) * UNITS + u], a0);
    a1 = fmaf(e[d + 1], Wxh[(d + 1) * UNITS + u], a1);
    a2 = fmaf(e[d + 2], Wxh[(d + 2) * UNITS + u], a2);
    a3 = fmaf(e[d + 3], Wxh[(d + 3) * UNITS + u], a3);
  }
  float cs = 0.f;
#pragma unroll
  for (int i = 0; i < UNITS; ++i) cs += Whh[i * UNITS + u];
  P[v * UNITS + u] = (((a0 + a1) + (a2 + a3)) + bias[u] + cs) * KSCALE;
}

// ---------------------------------------------------------------------------
// Kernel 2: sequential scan, ONE wave per batch row. Split-2 structure --
// the measured floor (492 cyc/step) across 7 structural variants tried in
// this session (split-2/4, no-split, register butterfly, DPP gather, 4-wave
// cooperative, fused-persistent). r-substitution shortens the serial tail:
// publish r = rcp(exp2(Ky)+1) instead of h (h = 1-2r), with colsum folded
// into P (proj) and -2K folded into the weight registers:
//   y_j = (x_j + b_j + colsum_j) - 2 sum_i r_i W_ij
// Chain: 8x ds_read_b128 -> 16 pk_fma (4 chains) -> permlane32_swap merge ->
// add -> exp2 -> add -> rcp -> ds_write. Initial state h=0 <=> r=0.5.
// ---------------------------------------------------------------------------
__global__ __launch_bounds__(64)
__attribute__((amdgpu_waves_per_eu(1, 1)))
void scan_kernel(
    const int* __restrict__ tok, const float* __restrict__ P,
    const float* __restrict__ Whh, const float* __restrict__ Wout,
    const float* __restrict__ bout, float* __restrict__ out) {
  const int row  = blockIdx.x;
  const int lane = threadIdx.x;
  const int g    = lane >> 5;   // which half of the i-dimension this lane sums
  const int m    = lane & 31;

  __shared__ __align__(16) v4f hs4[UNITS / 4];  // 64 floats (r-state)
  float* hsf = (float*)hs4;

  // Weights scaled by -2*KSCALE (the r-substitution + exp2 fold):
  //   wv0[k2] = -2K * {Whh[32g+2k2][m],    Whh[32g+2k2+1][m]}
  //   wv1[k2] = -2K * {Whh[32g+2k2][m+32], Whh[32g+2k2+1][m+32]}
  v2f wv0[UNITS / 4], wv1[UNITS / 4];
#pragma unroll
  for (int k2 = 0; k2 < UNITS / 4; ++k2) {
    const int i0 = 32 * g + 2 * k2;
    float ax = Whh[(i0 + 0) * UNITS + m] * (-2.f * KSCALE);
    float ay = Whh[(i0 + 1) * UNITS + m] * (-2.f * KSCALE);
    float bx = Whh[(i0 + 0) * UNITS + m + 32] * (-2.f * KSCALE);
    float by = Whh[(i0 + 1) * UNITS + m + 32] * (-2.f * KSCALE);
    asm volatile("" : "+v"(ax), "+v"(ay), "+v"(bx), "+v"(by));
    wv0[k2].x = ax; wv0[k2].y = ay;
    wv1[k2].x = bx; wv1[k2].y = by;
  }

  // All 512 tokens of this row, pre-scaled by UNITS (coalesced loads).
  int tokv[SEQ / 64];
  const int* trow = tok + (long)row * SEQ;
#pragma unroll
  for (int c = 0; c < SEQ / 64; ++c) {
    int t = trow[c * 64 + lane] * UNITS;
    asm volatile("" : "+v"(t));
    tokv[c] = t;
  }

  // h_0 = 0  <=>  r_0 = 0.5 (single wave: in-order DS pipe, no barriers).
  hsf[lane] = 0.5f;
  float r_last = 0.5f;

  // Prefetch P row for t=0.
  int tk0 = __builtin_amdgcn_readlane(tokv[0], 0);
  float a = P[(long)tk0 + lane];

#pragma unroll
  for (int c = 0; c < SEQ / 64; ++c) {
#pragma unroll 2
    for (int tt = 0; tt < 64; ++tt) {
      float a_cur = a;
      // Prefetch next timestep's P row (consumed one full step later).
      int ntt = (tt + 1) & 63;
      int tkn = __builtin_amdgcn_readlane(tokv[c], ntt);
      a = P[(long)tkn + lane];

      // ---- Read only MY half of r: 8x ds_read_b128, back-to-back. ----
      v4f hq[UNITS / 8];
#pragma unroll
      for (int q = 0; q < UNITS / 8; ++q) hq[q] = hs4[(UNITS / 8) * g + q];

      // ---- Two half-dot partials, 4 independent 8-deep pk_fma chains. ----
      v2f p0a = {0.f, 0.f}, p0b = {0.f, 0.f};
      v2f p1a = {0.f, 0.f}, p1b = {0.f, 0.f};
#pragma unroll
      for (int q = 0; q < UNITS / 8; ++q) {
        v2f lo = __builtin_shufflevector(hq[q], hq[q], 0, 1);
        v2f hi = __builtin_shufflevector(hq[q], hq[q], 2, 3);
        p0a += lo * wv0[2 * q + 0];
        p0b += hi * wv0[2 * q + 1];
        p1a += lo * wv1[2 * q + 0];
        p1b += hi * wv1[2 * q + 1];
      }
      float s0 = (p0a.x + p0a.y) + (p0b.x + p0b.y);  // partial of Ky[m]
      float s1 = (p1a.x + p1a.y) + (p1b.x + p1b.y);  // partial of Ky[m+32]

      // ---- Merge halves (r1-verified): y'[lane] = K*y[lane]. ----
      v2i sw = __builtin_amdgcn_permlane32_swap(
          __float_as_int(s0), __float_as_int(s1), false, false);
      float y = __int_as_float(sw[0]) + __int_as_float(sw[1]) + a_cur;

      // r = rcp(exp(2y)+1); h = 1-2r applied implicitly via weight/P folds.
      float ex = __builtin_amdgcn_exp2f(y);
      float r = __builtin_amdgcn_rcpf(ex + 1.f);
      r_last = r;

      // Publish r for the next step (in-order DS pipe, no barrier needed).
      hsf[lane] = r;
    }
    if (c + 1 < SEQ / 64) {
      int tkb = __builtin_amdgcn_readlane(tokv[c + 1], 0);
      a = P[(long)tkb + lane];
    }
  }

  // h_T[lane] = 1 - 2*r_last;  out[row] = sigmoid(h_T . Wout + bout)
  float hT = fmaf(-2.f, r_last, 1.f);
  float psum = hT * Wout[lane];
#pragma unroll
  for (int off = 32; off > 0; off >>= 1) psum += __shfl_xor(psum, off);
  if (lane == 0) out[row] = 1.f / (1.f + __expf(-(psum + bout[0])));
}

extern "C" void kernel_launch(void* const* d_in, const int* in_sizes, int n_in,
                              void* d_out, int out_size, void* d_ws, size_t ws_size,
                              hipStream_t stream) {
  const int*   tok  = (const int*)  d_in[0];  // [BATCH, SEQ] int32
  const float* emb  = (const float*)d_in[1];  // [VOCAB, EMB]
  const float* Wxh  = (const float*)d_in[2];  // [EMB, UNITS]
  const float* Whh  = (const float*)d_in[3];  // [UNITS, UNITS]
  const float* bias = (const float*)d_in[4];  // [UNITS]
  const float* Wout = (const float*)d_in[5];  // [UNITS, 1]
  const float* bout = (const float*)d_in[6];  // [1]
  float* out = (float*)d_out;                 // [BATCH, 1] fp32

  float* P = (float*)d_ws;                    // VOCAB*UNITS fp32 = 256 KB

  proj_kernel<<<VOCAB / 4, 256, 0, stream>>>(emb, Wxh, bias, Whh, P);
  scan_kernel<<<BATCH, 64, 0, stream>>>(tok, P, Whh, Wout, bout, out);
}